// Round 4
// baseline (645.373 us; speedup 1.0000x reference)
//
#include <hip/hip_runtime.h>
#include <math.h>

#define F 128
#define OUTDIM 64
#define NEG 0.2f
#define BN 128
#define KT2 32

// ---------------- utility ----------------
__global__ void zero_ints(int* __restrict__ p, int n) {
    int i = blockIdx.x * blockDim.x + threadIdx.x;
    if (i < n) p[i] = 0;
}

// ---------------- CSR build ----------------
__global__ void hist_kernel(const int* __restrict__ src, const int* __restrict__ dst,
                            int* __restrict__ degF, int* __restrict__ degR, int E) {
    int e = blockIdx.x * blockDim.x + threadIdx.x;
    if (e < E) {
        atomicAdd(&degF[dst[e]], 1);
        atomicAdd(&degR[src[e]], 1);
    }
}

__global__ void scan_pass1(const int* __restrict__ degF, const int* __restrict__ degR,
                           int* __restrict__ rsF, int* __restrict__ rsR,
                           int* __restrict__ bsums, int N) {
    const int arr = blockIdx.y;
    const int* deg = arr ? degR : degF;
    int* rs = arr ? rsR : rsF;
    int tid = threadIdx.x;
    int base = blockIdx.x * 1024 + tid * 4;
    int v[4];
#pragma unroll
    for (int i = 0; i < 4; i++) v[i] = (base + i < N) ? deg[base + i] : 0;
    int s1 = v[0] + v[1] + v[2] + v[3];
    __shared__ int sd[256];
    sd[tid] = s1;
    __syncthreads();
    for (int off = 1; off < 256; off <<= 1) {
        int t = (tid >= off) ? sd[tid - off] : 0;
        __syncthreads();
        sd[tid] += t;
        __syncthreads();
    }
    int run = sd[tid] - s1;
#pragma unroll
    for (int i = 0; i < 4; i++) {
        run += v[i];
        if (base + i < N) rs[base + i + 1] = run;
    }
    if (tid == 255) bsums[arr * 128 + blockIdx.x] = sd[255];
    if (tid == 0 && blockIdx.x == 0) rs[0] = 0;
}

__global__ void scan_pass2(int* __restrict__ bsums, int nb) {
    int arr = blockIdx.y;
    int tid = threadIdx.x;  // 128
    __shared__ int sd[128];
    int v = (tid < nb) ? bsums[arr * 128 + tid] : 0;
    sd[tid] = v;
    __syncthreads();
    for (int off = 1; off < 128; off <<= 1) {
        int t = (tid >= off) ? sd[tid - off] : 0;
        __syncthreads();
        sd[tid] += t;
        __syncthreads();
    }
    bsums[arr * 128 + tid] = sd[tid];
}

__global__ void scan_pass3(int* __restrict__ rsF, int* __restrict__ rsR,
                           const int* __restrict__ bsums, int N) {
    int arr = blockIdx.y;
    if (blockIdx.x == 0) return;
    int* rs = arr ? rsR : rsF;
    int off = bsums[arr * 128 + blockIdx.x - 1];
    int base = blockIdx.x * 1024 + threadIdx.x * 4;
#pragma unroll
    for (int i = 0; i < 4; i++)
        if (base + i < N) rs[base + i + 1] += off;
}

__global__ void scatter_kernel(const int* __restrict__ src, const int* __restrict__ dst,
                               const int* __restrict__ rsF, const int* __restrict__ rsR,
                               int* __restrict__ curF, int* __restrict__ curR,
                               int* __restrict__ colF, int* __restrict__ colR, int E) {
    int e = blockIdx.x * blockDim.x + threadIdx.x;
    if (e < E) {
        int s = src[e], d = dst[e];
        int pf = rsF[d] + atomicAdd(&curF[d], 1);
        colF[pf] = s;
        int pr = rsR[s] + atomicAdd(&curR[s], 1);
        colR[pr] = d;
    }
}

// ---------------- per-node attention scalars ----------------
__global__ void sd4_kernel(const float* __restrict__ x,
                           const float* __restrict__ af_s, const float* __restrict__ af_d,
                           const float* __restrict__ ar_s, const float* __restrict__ ar_d,
                           float* __restrict__ sf, float* __restrict__ df,
                           float* __restrict__ sr, float* __restrict__ dr, int N) {
    int node = blockIdx.x * 4 + (threadIdx.x >> 6);
    int lane = threadIdx.x & 63;
    if (node >= N) return;
    const float2 xv = *(const float2*)&x[(size_t)node * F + 2 * lane];
    float2 a;
    a = *(const float2*)&af_s[2 * lane]; float vsf = xv.x * a.x + xv.y * a.y;
    a = *(const float2*)&af_d[2 * lane]; float vdf = xv.x * a.x + xv.y * a.y;
    a = *(const float2*)&ar_s[2 * lane]; float vsr = xv.x * a.x + xv.y * a.y;
    a = *(const float2*)&ar_d[2 * lane]; float vdr = xv.x * a.x + xv.y * a.y;
#pragma unroll
    for (int off = 32; off > 0; off >>= 1) {
        vsf += __shfl_xor(vsf, off);
        vdf += __shfl_xor(vdf, off);
        vsr += __shfl_xor(vsr, off);
        vdr += __shfl_xor(vdr, off);
    }
    if (lane == 0) { sf[node] = vsf; df[node] = vdf; sr[node] = vsr; dr[node] = vdr; }
}

// ---------------- fused dual-direction attention hop ----------------
// half-wave (32 lanes x float4) per node; blockIdx.y selects direction.
struct AggDir {
    const float* hin;   // [N][128]
    const float* s;     // [N]
    const float* d;     // [N]
    const int* rs;      // [N+1]
    const int* col;     // [E]
    float* hout;        // [N][128]
    const float* a_s;   // nullable: fused next-hop dots
    const float* a_d;
    float* s_out;
    float* d_out;
};

__global__ __launch_bounds__(256) void agg_kernel(AggDir D0, AggDir D1, int N) {
    AggDir P = blockIdx.y ? D1 : D0;
    int node = blockIdx.x * 8 + (threadIdx.x >> 5);
    int lane = threadIdx.x & 31;           // within half-wave
    int sbase = threadIdx.x & 32;          // half offset inside the wave
    if (node >= N) return;
    float di = P.d[node];
    int beg = P.rs[node], end = P.rs[node + 1];
    int deg = end - beg;
    float m = -INFINITY, l = 0.f;
    float ax = 0.f, ay = 0.f, az = 0.f, aw = 0.f;

    for (int base = 0; base < deg; base += 32) {
        int cnt = min(32, deg - base);
        int sj_l = 0;
        float e_l = -INFINITY;
        if (lane < cnt) {
            sj_l = P.col[beg + base + lane];
            float e = P.s[sj_l] + di;
            e_l = (e >= 0.f) ? e : NEG * e;
        }
        float bm = e_l;
#pragma unroll
        for (int off = 16; off > 0; off >>= 1) bm = fmaxf(bm, __shfl_xor(bm, off));
        float nm = fmaxf(m, bm);
        float p_l = (lane < cnt) ? __expf(e_l - nm) : 0.f;
        float ps = p_l;
#pragma unroll
        for (int off = 16; off > 0; off >>= 1) ps += __shfl_xor(ps, off);
        float sc = (m == -INFINITY) ? 0.f : __expf(m - nm);
        l = l * sc + ps;
        ax *= sc; ay *= sc; az *= sc; aw *= sc;
        // 4-deep pipelined weighted row gather (p=0 for pad lanes -> harmless row-0 loads)
        for (int j0 = 0; j0 < cnt; j0 += 4) {
            int s0 = __shfl(sj_l, sbase + j0 + 0); float p0 = __shfl(p_l, sbase + j0 + 0);
            int s1 = __shfl(sj_l, sbase + j0 + 1); float p1 = __shfl(p_l, sbase + j0 + 1);
            int s2 = __shfl(sj_l, sbase + j0 + 2); float p2 = __shfl(p_l, sbase + j0 + 2);
            int s3 = __shfl(sj_l, sbase + j0 + 3); float p3 = __shfl(p_l, sbase + j0 + 3);
            float4 h0 = *(const float4*)&P.hin[(size_t)s0 * F + 4 * lane];
            float4 h1 = *(const float4*)&P.hin[(size_t)s1 * F + 4 * lane];
            float4 h2 = *(const float4*)&P.hin[(size_t)s2 * F + 4 * lane];
            float4 h3 = *(const float4*)&P.hin[(size_t)s3 * F + 4 * lane];
            ax += p0 * h0.x + p1 * h1.x + p2 * h2.x + p3 * h3.x;
            ay += p0 * h0.y + p1 * h1.y + p2 * h2.y + p3 * h3.y;
            az += p0 * h0.z + p1 * h1.z + p2 * h2.z + p3 * h3.z;
            aw += p0 * h0.w + p1 * h1.w + p2 * h2.w + p3 * h3.w;
        }
        m = nm;
    }

    float4 o;
    if (deg > 0) {
        float inv = 1.f / (l + 1e-16f);
        o.x = ax * inv; o.y = ay * inv; o.z = az * inv; o.w = aw * inv;
    } else {
        o.x = o.y = o.z = o.w = 0.f;
    }
    *(float4*)&P.hout[(size_t)node * F + 4 * lane] = o;
    if (P.a_s) {
        float4 a;
        a = *(const float4*)&P.a_s[4 * lane];
        float vs = o.x * a.x + o.y * a.y + o.z * a.z + o.w * a.w;
        a = *(const float4*)&P.a_d[4 * lane];
        float vd = o.x * a.x + o.y * a.y + o.z * a.z + o.w * a.w;
#pragma unroll
        for (int off = 16; off > 0; off >>= 1) {
            vs += __shfl_xor(vs, off);
            vd += __shfl_xor(vd, off);
        }
        if (lane == 0) { P.s_out[node] = vs; P.d_out[node] = vd; }
    }
}

// ---------------- fold W blocks: Weff[640][64] ----------------
__global__ void weff_kernel(const float* __restrict__ W, float* __restrict__ Weff) {
    int i = blockIdx.x * blockDim.x + threadIdx.x;
    if (i >= 640 * 64) return;
    int r = i >> 6, o = i & 63;
    float v;
    if (r < 128)      v = W[r * 64 + o] + W[(r + 384) * 64 + o];
    else if (r < 384) v = W[r * 64 + o];
    else              v = W[(r + 128) * 64 + o];
    Weff[i] = v;
}

// ---------------- final dense: out = [x|h1f|h2f|h1r|h2r] @ Weff + b ----------------
// Double-buffered LDS, register prefetch, one barrier per tile.
__global__ __launch_bounds__(256) void gemm_kernel(
    const float* __restrict__ X0, const float* __restrict__ H1F,
    const float* __restrict__ H2F, const float* __restrict__ H1R,
    const float* __restrict__ H2R,
    const float* __restrict__ Weff, const float* __restrict__ bias,
    float* __restrict__ out, int N) {
    __shared__ float Xs[2][KT2][BN + 4];
    __shared__ float Ws[2][KT2][68];
    const float* srcs[5] = {X0, H1F, H2F, H1R, H2R};
    int tid = threadIdx.x;
    int tx = tid & 15, ty = tid >> 4;
    int nodeBase = blockIdx.x * BN;
    int srow = tid >> 1;          // 0..127
    int half = tid & 1;
    int rowx = srow ^ (half << 4);
    int kb = half * 16;
    int wf0 = 2 * tid;            // W stage flat index
    float acc[8][4];
#pragma unroll
    for (int i = 0; i < 8; i++)
#pragma unroll
        for (int j = 0; j < 4; j++) acc[i][j] = 0.f;
    float4 rx[4], rw[2];

#define LOAD_TILE(t)                                                            \
    {                                                                           \
        const float* srcp = srcs[(t) >> 2];                                     \
        int cb = ((t) & 3) * 32;                                                \
        int n = nodeBase + srow;                                                \
        if (n < N) {                                                            \
            const float* p = srcp + (size_t)n * 128 + cb + kb;                  \
            rx[0] = *(const float4*)(p);                                        \
            rx[1] = *(const float4*)(p + 4);                                    \
            rx[2] = *(const float4*)(p + 8);                                    \
            rx[3] = *(const float4*)(p + 12);                                   \
        } else {                                                                \
            rx[0] = rx[1] = rx[2] = rx[3] = make_float4(0.f, 0.f, 0.f, 0.f);    \
        }                                                                       \
        rw[0] = *(const float4*)&Weff[(size_t)((t)*32 + (wf0 >> 4)) * 64 + (wf0 & 15) * 4];          \
        rw[1] = *(const float4*)&Weff[(size_t)((t)*32 + ((wf0 + 1) >> 4)) * 64 + ((wf0 + 1) & 15) * 4]; \
    }
#define WRITE_TILE(b)                                                           \
    {                                                                           \
        _Pragma("unroll")                                                       \
        for (int q = 0; q < 4; q++) {                                           \
            Xs[b][kb + q * 4 + 0][rowx] = rx[q].x;                              \
            Xs[b][kb + q * 4 + 1][rowx] = rx[q].y;                              \
            Xs[b][kb + q * 4 + 2][rowx] = rx[q].z;                              \
            Xs[b][kb + q * 4 + 3][rowx] = rx[q].w;                              \
        }                                                                       \
        *(float4*)&Ws[b][wf0 >> 4][(wf0 & 15) * 4] = rw[0];                     \
        *(float4*)&Ws[b][(wf0 + 1) >> 4][((wf0 + 1) & 15) * 4] = rw[1];         \
    }

    LOAD_TILE(0);
    WRITE_TILE(0);
    int cur = 0;
    for (int t = 0; t < 20; ++t) {
        if (t < 19) LOAD_TILE(t + 1);
        __syncthreads();
#pragma unroll
        for (int k = 0; k < KT2; k++) {
            const int flip = (k >> 4) << 4;
            float4 x0 = *(const float4*)&Xs[cur][k][(ty * 8) ^ flip];
            float4 x1 = *(const float4*)&Xs[cur][k][(ty * 8 + 4) ^ flip];
            float4 w4 = *(const float4*)&Ws[cur][k][tx * 4];
            float xv[8] = {x0.x, x0.y, x0.z, x0.w, x1.x, x1.y, x1.z, x1.w};
            float wv[4] = {w4.x, w4.y, w4.z, w4.w};
#pragma unroll
            for (int i = 0; i < 8; i++)
#pragma unroll
                for (int j = 0; j < 4; j++) acc[i][j] += xv[i] * wv[j];
        }
        if (t < 19) WRITE_TILE(cur ^ 1);
        cur ^= 1;
    }
    float4 bv = *(const float4*)&bias[tx * 4];
#pragma unroll
    for (int i = 0; i < 8; i++) {
        int n = nodeBase + ty * 8 + i;
        if (n < N) {
            float4 o;
            o.x = acc[i][0] + bv.x; o.y = acc[i][1] + bv.y;
            o.z = acc[i][2] + bv.z; o.w = acc[i][3] + bv.w;
            *(float4*)&out[(size_t)n * 64 + tx * 4] = o;
        }
    }
#undef LOAD_TILE
#undef WRITE_TILE
}

extern "C" void kernel_launch(void* const* d_in, const int* in_sizes, int n_in,
                              void* d_out, int out_size, void* d_ws, size_t ws_size,
                              hipStream_t stream) {
    const float* feature = (const float*)d_in[0];
    const int*   eidx    = (const int*)d_in[1];
    const float* af_s    = (const float*)d_in[2];
    const float* af_d    = (const float*)d_in[3];
    const float* ar_s    = (const float*)d_in[4];
    const float* ar_d    = (const float*)d_in[5];
    const float* W       = (const float*)d_in[6];
    const float* bias    = (const float*)d_in[7];
    float* out = (float*)d_out;
    const int N = in_sizes[0] / F;
    const int E = in_sizes[1] / 2;
    const int* src = eidx;
    const int* dst = eidx + E;

    char* ws = (char*)d_ws;
    size_t off = 0;
    auto alloc = [&](size_t b) { size_t r = off; off = (off + b + 255) & ~(size_t)255; return r; };
    float* h1f = (float*)(ws + alloc((size_t)N * F * 4));
    float* h2f = (float*)(ws + alloc((size_t)N * F * 4));
    float* h1r = (float*)(ws + alloc((size_t)N * F * 4));
    float* h2r = (float*)(ws + alloc((size_t)N * F * 4));
    int*   rsF   = (int*)(ws + alloc((size_t)(N + 1) * 4));
    int*   rsR   = (int*)(ws + alloc((size_t)(N + 1) * 4));
    int*   colF  = (int*)(ws + alloc((size_t)E * 4));
    int*   colR  = (int*)(ws + alloc((size_t)E * 4));
    int*   ints4 = (int*)(ws + alloc((size_t)4 * N * 4));
    int *degF = ints4, *degR = ints4 + N, *curF = ints4 + 2 * N, *curR = ints4 + 3 * N;
    float* fls8 = (float*)(ws + alloc((size_t)8 * N * 4));
    float *sf = fls8, *df = fls8 + N, *sr = fls8 + 2 * (size_t)N, *dr = fls8 + 3 * (size_t)N;
    float *s2f = fls8 + 4 * (size_t)N, *d2f = fls8 + 5 * (size_t)N;
    float *s2r = fls8 + 6 * (size_t)N, *d2r = fls8 + 7 * (size_t)N;
    int*   bsums = (int*)(ws + alloc(256 * 4));
    float* Weff  = (float*)(ws + alloc(640 * 64 * 4));

    const int nb = (N + 1023) / 1024;
    zero_ints<<<(4 * N + 255) / 256, 256, 0, stream>>>(ints4, 4 * N);
    hist_kernel<<<(E + 255) / 256, 256, 0, stream>>>(src, dst, degF, degR, E);
    scan_pass1<<<dim3(nb, 2), 256, 0, stream>>>(degF, degR, rsF, rsR, bsums, N);
    scan_pass2<<<dim3(1, 2), 128, 0, stream>>>(bsums, nb);
    scan_pass3<<<dim3(nb, 2), 256, 0, stream>>>(rsF, rsR, bsums, N);
    scatter_kernel<<<(E + 255) / 256, 256, 0, stream>>>(src, dst, rsF, rsR, curF, curR, colF, colR, E);
    sd4_kernel<<<(N + 3) / 4, 256, 0, stream>>>(feature, af_s, af_d, ar_s, ar_d, sf, df, sr, dr, N);

    AggDir F1{feature, sf, df, rsF, colF, h1f, af_s, af_d, s2f, d2f};
    AggDir R1{feature, sr, dr, rsR, colR, h1r, ar_s, ar_d, s2r, d2r};
    agg_kernel<<<dim3((N + 7) / 8, 2), 256, 0, stream>>>(F1, R1, N);
    AggDir F2{h1f, s2f, d2f, rsF, colF, h2f, nullptr, nullptr, nullptr, nullptr};
    AggDir R2{h1r, s2r, d2r, rsR, colR, h2r, nullptr, nullptr, nullptr, nullptr};
    agg_kernel<<<dim3((N + 7) / 8, 2), 256, 0, stream>>>(F2, R2, N);

    weff_kernel<<<(640 * 64 + 255) / 256, 256, 0, stream>>>(W, Weff);
    gemm_kernel<<<(N + BN - 1) / BN, 256, 0, stream>>>(feature, h1f, h2f, h1r, h2r, Weff, bias, out, N);
}

// Round 5
// 532.944 us; speedup vs baseline: 1.2110x; 1.2110x over previous
//
#include <hip/hip_runtime.h>
#include <math.h>

#define F 128
#define OUTDIM 64
#define NEG 0.2f
#define BN 128
#define KT2 32

// ---------------- utility ----------------
__global__ void zero_ints(int* __restrict__ p, int n) {
    int i = blockIdx.x * blockDim.x + threadIdx.x;
    if (i < n) p[i] = 0;
}

// ---------------- CSR build ----------------
__global__ void hist_kernel(const int* __restrict__ src, const int* __restrict__ dst,
                            int* __restrict__ degF, int* __restrict__ degR, int E) {
    int e = blockIdx.x * blockDim.x + threadIdx.x;
    if (e < E) {
        atomicAdd(&degF[dst[e]], 1);
        atomicAdd(&degR[src[e]], 1);
    }
}

__global__ void scan_pass1(const int* __restrict__ degF, const int* __restrict__ degR,
                           int* __restrict__ rsF, int* __restrict__ rsR,
                           int* __restrict__ bsums, int N) {
    const int arr = blockIdx.y;
    const int* deg = arr ? degR : degF;
    int* rs = arr ? rsR : rsF;
    int tid = threadIdx.x;
    int base = blockIdx.x * 1024 + tid * 4;
    int v[4];
#pragma unroll
    for (int i = 0; i < 4; i++) v[i] = (base + i < N) ? deg[base + i] : 0;
    int s1 = v[0] + v[1] + v[2] + v[3];
    __shared__ int sd[256];
    sd[tid] = s1;
    __syncthreads();
    for (int off = 1; off < 256; off <<= 1) {
        int t = (tid >= off) ? sd[tid - off] : 0;
        __syncthreads();
        sd[tid] += t;
        __syncthreads();
    }
    int run = sd[tid] - s1;
#pragma unroll
    for (int i = 0; i < 4; i++) {
        run += v[i];
        if (base + i < N) rs[base + i + 1] = run;
    }
    if (tid == 255) bsums[arr * 128 + blockIdx.x] = sd[255];
    if (tid == 0 && blockIdx.x == 0) rs[0] = 0;
}

__global__ void scan_pass2(int* __restrict__ bsums, int nb) {
    int arr = blockIdx.y;
    int tid = threadIdx.x;  // 128
    __shared__ int sd[128];
    int v = (tid < nb) ? bsums[arr * 128 + tid] : 0;
    sd[tid] = v;
    __syncthreads();
    for (int off = 1; off < 128; off <<= 1) {
        int t = (tid >= off) ? sd[tid - off] : 0;
        __syncthreads();
        sd[tid] += t;
        __syncthreads();
    }
    bsums[arr * 128 + tid] = sd[tid];
}

__global__ void scan_pass3(int* __restrict__ rsF, int* __restrict__ rsR,
                           const int* __restrict__ bsums, int N) {
    int arr = blockIdx.y;
    if (blockIdx.x == 0) return;
    int* rs = arr ? rsR : rsF;
    int off = bsums[arr * 128 + blockIdx.x - 1];
    int base = blockIdx.x * 1024 + threadIdx.x * 4;
#pragma unroll
    for (int i = 0; i < 4; i++)
        if (base + i < N) rs[base + i + 1] += off;
}

__global__ void scatter_kernel(const int* __restrict__ src, const int* __restrict__ dst,
                               const int* __restrict__ rsF, const int* __restrict__ rsR,
                               int* __restrict__ curF, int* __restrict__ curR,
                               int* __restrict__ colF, int* __restrict__ colR, int E) {
    int e = blockIdx.x * blockDim.x + threadIdx.x;
    if (e < E) {
        int s = src[e], d = dst[e];
        int pf = rsF[d] + atomicAdd(&curF[d], 1);
        colF[pf] = s;
        int pr = rsR[s] + atomicAdd(&curR[s], 1);
        colR[pr] = d;
    }
}

// ---------------- per-node attention scalars ----------------
__global__ void sd4_kernel(const float* __restrict__ x,
                           const float* __restrict__ af_s, const float* __restrict__ af_d,
                           const float* __restrict__ ar_s, const float* __restrict__ ar_d,
                           float* __restrict__ sf, float* __restrict__ df,
                           float* __restrict__ sr, float* __restrict__ dr, int N) {
    int node = blockIdx.x * 4 + (threadIdx.x >> 6);
    int lane = threadIdx.x & 63;
    if (node >= N) return;
    const float2 xv = *(const float2*)&x[(size_t)node * F + 2 * lane];
    float2 a;
    a = *(const float2*)&af_s[2 * lane]; float vsf = xv.x * a.x + xv.y * a.y;
    a = *(const float2*)&af_d[2 * lane]; float vdf = xv.x * a.x + xv.y * a.y;
    a = *(const float2*)&ar_s[2 * lane]; float vsr = xv.x * a.x + xv.y * a.y;
    a = *(const float2*)&ar_d[2 * lane]; float vdr = xv.x * a.x + xv.y * a.y;
#pragma unroll
    for (int off = 32; off > 0; off >>= 1) {
        vsf += __shfl_xor(vsf, off);
        vdf += __shfl_xor(vdf, off);
        vsr += __shfl_xor(vsr, off);
        vdr += __shfl_xor(vdr, off);
    }
    if (lane == 0) { sf[node] = vsf; df[node] = vdf; sr[node] = vsr; dr[node] = vdr; }
}

// ---------------- fused dual-direction attention hop ----------------
// half-wave (32 lanes x float4) per node; blockIdx.y selects direction.
// 8-deep pipelined row gather.
struct AggDir {
    const float* hin;   // [N][128]
    const float* s;     // [N]
    const float* d;     // [N]
    const int* rs;      // [N+1]
    const int* col;     // [E]
    float* hout;        // [N][128]
    const float* a_s;   // nullable: fused next-hop dots
    const float* a_d;
    float* s_out;
    float* d_out;
};

__global__ __launch_bounds__(256) void agg_kernel(AggDir D0, AggDir D1, int N) {
    AggDir P = blockIdx.y ? D1 : D0;
    int node = blockIdx.x * 8 + (threadIdx.x >> 5);
    int lane = threadIdx.x & 31;           // within half-wave
    int sbase = threadIdx.x & 32;          // half offset inside the wave
    if (node >= N) return;
    float di = P.d[node];
    int beg = P.rs[node], end = P.rs[node + 1];
    int deg = end - beg;
    float m = -INFINITY, l = 0.f;
    float ax = 0.f, ay = 0.f, az = 0.f, aw = 0.f;

    for (int base = 0; base < deg; base += 32) {
        int cnt = min(32, deg - base);
        int sj_l = 0;
        float e_l = -INFINITY;
        if (lane < cnt) {
            sj_l = P.col[beg + base + lane];
            float e = P.s[sj_l] + di;
            e_l = (e >= 0.f) ? e : NEG * e;
        }
        float bm = e_l;
#pragma unroll
        for (int off = 16; off > 0; off >>= 1) bm = fmaxf(bm, __shfl_xor(bm, off));
        float nm = fmaxf(m, bm);
        float p_l = (lane < cnt) ? __expf(e_l - nm) : 0.f;
        float ps = p_l;
#pragma unroll
        for (int off = 16; off > 0; off >>= 1) ps += __shfl_xor(ps, off);
        float sc = (m == -INFINITY) ? 0.f : __expf(m - nm);
        l = l * sc + ps;
        ax *= sc; ay *= sc; az *= sc; aw *= sc;
        // 8-deep pipelined weighted row gather (p=0 for pad lanes -> harmless row-0 loads)
        for (int j0 = 0; j0 < cnt; j0 += 8) {
            int sj[8]; float p[8]; float4 h[8];
#pragma unroll
            for (int u = 0; u < 8; u++) {
                sj[u] = __shfl(sj_l, sbase + j0 + u);
                p[u]  = __shfl(p_l,  sbase + j0 + u);
            }
#pragma unroll
            for (int u = 0; u < 8; u++)
                h[u] = *(const float4*)&P.hin[(size_t)sj[u] * F + 4 * lane];
#pragma unroll
            for (int u = 0; u < 8; u++) {
                ax += p[u] * h[u].x;
                ay += p[u] * h[u].y;
                az += p[u] * h[u].z;
                aw += p[u] * h[u].w;
            }
        }
        m = nm;
    }

    float4 o;
    if (deg > 0) {
        float inv = 1.f / (l + 1e-16f);
        o.x = ax * inv; o.y = ay * inv; o.z = az * inv; o.w = aw * inv;
    } else {
        o.x = o.y = o.z = o.w = 0.f;
    }
    *(float4*)&P.hout[(size_t)node * F + 4 * lane] = o;
    if (P.a_s) {
        float4 a;
        a = *(const float4*)&P.a_s[4 * lane];
        float vs = o.x * a.x + o.y * a.y + o.z * a.z + o.w * a.w;
        a = *(const float4*)&P.a_d[4 * lane];
        float vd = o.x * a.x + o.y * a.y + o.z * a.z + o.w * a.w;
#pragma unroll
        for (int off = 16; off > 0; off >>= 1) {
            vs += __shfl_xor(vs, off);
            vd += __shfl_xor(vd, off);
        }
        if (lane == 0) { P.s_out[node] = vs; P.d_out[node] = vd; }
    }
}

// ---------------- fold W blocks: Weff[640][64] ----------------
__global__ void weff_kernel(const float* __restrict__ W, float* __restrict__ Weff) {
    int i = blockIdx.x * blockDim.x + threadIdx.x;
    if (i >= 640 * 64) return;
    int r = i >> 6, o = i & 63;
    float v;
    if (r < 128)      v = W[r * 64 + o] + W[(r + 384) * 64 + o];
    else if (r < 384) v = W[r * 64 + o];
    else              v = W[(r + 128) * 64 + o];
    Weff[i] = v;
}

// ---------------- final dense: out = [x|h1f|h2f|h1r|h2r] @ Weff + b ----------------
// 512 threads (8 waves/block -> 24 waves/CU at 3 blocks/CU), 4x4 micro-tile,
// single-buffered KT=32. X staged transposed, swizzled rowx = srow ^ (q<<4):
// per scalar-write the 64 lanes cover 32 banks x2 = free. Read flip = (k>>3)<<4.
__global__ __launch_bounds__(512) void gemm_kernel(
    const float* __restrict__ X0, const float* __restrict__ H1F,
    const float* __restrict__ H2F, const float* __restrict__ H1R,
    const float* __restrict__ H2R,
    const float* __restrict__ Weff, const float* __restrict__ bias,
    float* __restrict__ out, int N) {
    __shared__ float Xs[KT2][BN + 4];  // 32 x 132
    __shared__ float Ws[KT2][68];
    const float* srcs[5] = {X0, H1F, H2F, H1R, H2R};
    int tid = threadIdx.x;
    int tx = tid & 15, ty = tid >> 4;   // ty 0..31
    int nodeBase = blockIdx.x * BN;
    int srow = tid >> 2;                // 0..127
    int q = tid & 3;                    // k-quarter (8 k each)
    int rowx = srow ^ (q << 4);
    float acc[4][4];
#pragma unroll
    for (int i = 0; i < 4; i++)
#pragma unroll
        for (int j = 0; j < 4; j++) acc[i][j] = 0.f;

    for (int t = 0; t < 20; ++t) {
        const float* srcp = srcs[t >> 2];
        int cb = (t & 3) * 32;
        // stage X: thread loads 8 consecutive k (two float4) of one row
        {
            int n = nodeBase + srow;
            int kb = q * 8;
            float4 v0, v1;
            if (n < N) {
                const float* p = srcp + (size_t)n * 128 + cb + kb;
                v0 = *(const float4*)(p);
                v1 = *(const float4*)(p + 4);
            } else {
                v0 = make_float4(0.f, 0.f, 0.f, 0.f);
                v1 = v0;
            }
            Xs[kb + 0][rowx] = v0.x;
            Xs[kb + 1][rowx] = v0.y;
            Xs[kb + 2][rowx] = v0.z;
            Xs[kb + 3][rowx] = v0.w;
            Xs[kb + 4][rowx] = v1.x;
            Xs[kb + 5][rowx] = v1.y;
            Xs[kb + 6][rowx] = v1.z;
            Xs[kb + 7][rowx] = v1.w;
        }
        // stage W: one float4 per thread
        {
            int wr = tid >> 4, wc4 = tid & 15;
            *(float4*)&Ws[wr][wc4 * 4] =
                *(const float4*)&Weff[(size_t)(t * 32 + wr) * 64 + wc4 * 4];
        }
        __syncthreads();
#pragma unroll
        for (int k = 0; k < KT2; k++) {
            const int flip = (k >> 3) << 4;
            float4 x4 = *(const float4*)&Xs[k][(ty * 4) ^ flip];
            float4 w4 = *(const float4*)&Ws[k][tx * 4];
            float xv[4] = {x4.x, x4.y, x4.z, x4.w};
            float wv[4] = {w4.x, w4.y, w4.z, w4.w};
#pragma unroll
            for (int i = 0; i < 4; i++)
#pragma unroll
                for (int j = 0; j < 4; j++) acc[i][j] += xv[i] * wv[j];
        }
        __syncthreads();
    }
    float4 bv = *(const float4*)&bias[tx * 4];
#pragma unroll
    for (int i = 0; i < 4; i++) {
        int n = nodeBase + ty * 4 + i;
        if (n < N) {
            float4 o;
            o.x = acc[i][0] + bv.x; o.y = acc[i][1] + bv.y;
            o.z = acc[i][2] + bv.z; o.w = acc[i][3] + bv.w;
            *(float4*)&out[(size_t)n * 64 + tx * 4] = o;
        }
    }
}

extern "C" void kernel_launch(void* const* d_in, const int* in_sizes, int n_in,
                              void* d_out, int out_size, void* d_ws, size_t ws_size,
                              hipStream_t stream) {
    const float* feature = (const float*)d_in[0];
    const int*   eidx    = (const int*)d_in[1];
    const float* af_s    = (const float*)d_in[2];
    const float* af_d    = (const float*)d_in[3];
    const float* ar_s    = (const float*)d_in[4];
    const float* ar_d    = (const float*)d_in[5];
    const float* W       = (const float*)d_in[6];
    const float* bias    = (const float*)d_in[7];
    float* out = (float*)d_out;
    const int N = in_sizes[0] / F;
    const int E = in_sizes[1] / 2;
    const int* src = eidx;
    const int* dst = eidx + E;

    char* ws = (char*)d_ws;
    size_t off = 0;
    auto alloc = [&](size_t b) { size_t r = off; off = (off + b + 255) & ~(size_t)255; return r; };
    float* h1f = (float*)(ws + alloc((size_t)N * F * 4));
    float* h2f = (float*)(ws + alloc((size_t)N * F * 4));
    float* h1r = (float*)(ws + alloc((size_t)N * F * 4));
    float* h2r = (float*)(ws + alloc((size_t)N * F * 4));
    int*   rsF   = (int*)(ws + alloc((size_t)(N + 1) * 4));
    int*   rsR   = (int*)(ws + alloc((size_t)(N + 1) * 4));
    int*   colF  = (int*)(ws + alloc((size_t)E * 4));
    int*   colR  = (int*)(ws + alloc((size_t)E * 4));
    int*   ints4 = (int*)(ws + alloc((size_t)4 * N * 4));
    int *degF = ints4, *degR = ints4 + N, *curF = ints4 + 2 * N, *curR = ints4 + 3 * N;
    float* fls8 = (float*)(ws + alloc((size_t)8 * N * 4));
    float *sf = fls8, *df = fls8 + N, *sr = fls8 + 2 * (size_t)N, *dr = fls8 + 3 * (size_t)N;
    float *s2f = fls8 + 4 * (size_t)N, *d2f = fls8 + 5 * (size_t)N;
    float *s2r = fls8 + 6 * (size_t)N, *d2r = fls8 + 7 * (size_t)N;
    int*   bsums = (int*)(ws + alloc(256 * 4));
    float* Weff  = (float*)(ws + alloc(640 * 64 * 4));

    const int nb = (N + 1023) / 1024;
    zero_ints<<<(4 * N + 255) / 256, 256, 0, stream>>>(ints4, 4 * N);
    hist_kernel<<<(E + 255) / 256, 256, 0, stream>>>(src, dst, degF, degR, E);
    scan_pass1<<<dim3(nb, 2), 256, 0, stream>>>(degF, degR, rsF, rsR, bsums, N);
    scan_pass2<<<dim3(1, 2), 128, 0, stream>>>(bsums, nb);
    scan_pass3<<<dim3(nb, 2), 256, 0, stream>>>(rsF, rsR, bsums, N);
    scatter_kernel<<<(E + 255) / 256, 256, 0, stream>>>(src, dst, rsF, rsR, curF, curR, colF, colR, E);
    sd4_kernel<<<(N + 3) / 4, 256, 0, stream>>>(feature, af_s, af_d, ar_s, ar_d, sf, df, sr, dr, N);

    AggDir F1{feature, sf, df, rsF, colF, h1f, af_s, af_d, s2f, d2f};
    AggDir R1{feature, sr, dr, rsR, colR, h1r, ar_s, ar_d, s2r, d2r};
    agg_kernel<<<dim3((N + 7) / 8, 2), 256, 0, stream>>>(F1, R1, N);
    AggDir F2{h1f, s2f, d2f, rsF, colF, h2f, nullptr, nullptr, nullptr, nullptr};
    AggDir R2{h1r, s2r, d2r, rsR, colR, h2r, nullptr, nullptr, nullptr, nullptr};
    agg_kernel<<<dim3((N + 7) / 8, 2), 256, 0, stream>>>(F2, R2, N);

    weff_kernel<<<(640 * 64 + 255) / 256, 256, 0, stream>>>(W, Weff);
    gemm_kernel<<<(N + BN - 1) / BN, 512, 0, stream>>>(feature, h1f, h2f, h1r, h2r, Weff, bias, out, N);
}